// Round 7
// baseline (233.192 us; speedup 1.0000x reference)
//
#include <hip/hip_runtime.h>
#include <math.h>

#define N_PIX 4096   // H*W
#define C_CH  256
#define NH    4
#define DH    64

typedef __attribute__((ext_vector_type(8))) short bf16x8;
typedef __attribute__((ext_vector_type(4))) float f32x4;

static __device__ __forceinline__ unsigned short f2bf(float f) {
  union { float f; unsigned u; } v; v.f = f;
  unsigned r = v.u + 0x7fffu + ((v.u >> 16) & 1u);  // RNE
  return (unsigned short)(r >> 16);
}
static __device__ __forceinline__ unsigned pk2(float a, float b) {
  return (unsigned)f2bf(a) | ((unsigned)f2bf(b) << 16);
}
// trunc-pack two fp32 -> bf16 pair in ONE v_perm_b32
static __device__ __forceinline__ unsigned pk2t(float a, float b) {
  return __builtin_amdgcn_perm(__float_as_uint(b), __float_as_uint(a),
                               0x07060302u);
}
#if __has_builtin(__builtin_amdgcn_exp2f)
#define EXP2(x) __builtin_amdgcn_exp2f(x)
#else
#define EXP2(x) exp2f(x)
#endif
// XOR-swizzled LDS offset (bf16 elems): rows of 64 elems, 8 granules of 8.
static __device__ __forceinline__ int swz(int row, int g) {
  return (row << 6) + ((((row >> 2) ^ row ^ g) & 7) << 3);
}

// ---------------------------------------------------------------------------
// GroupNorm stage A (partial sums) + weight fp32->bf16 convert (fused).
// ---------------------------------------------------------------------------
__global__ __launch_bounds__(256) void gn_part_kernel(
    const float* __restrict__ x, const float* __restrict__ wqkv,
    const float* __restrict__ wproj, float* __restrict__ part,
    unsigned short* __restrict__ wB) {
  const int g = blockIdx.x, b = blockIdx.y, z = blockIdx.z;
  const int t = threadIdx.x;
  {
    const int bid = blockIdx.z * 32 + blockIdx.y * 8 + blockIdx.x;
    const int i = bid * 256 + t;
    const float* src = (i < 49152) ? (wqkv + (size_t)i * 4)
                                   : (wproj + (size_t)(i - 49152) * 4);
    float4 v = *(const float4*)src;
    uint2 u;
    u.x = pk2(v.x, v.y);
    u.y = pk2(v.z, v.w);
    *(uint2*)(wB + (size_t)i * 4) = u;
  }
  const float* base = x + (size_t)(b * C_CH + g * 32 + z * 4) * N_PIX;
  float sum = 0.f, sq = 0.f;
  for (int i = t * 4; i < 4 * N_PIX; i += 256 * 4) {
    float4 v = *(const float4*)(base + i);
    sum += v.x + v.y + v.z + v.w;
    sq  += v.x * v.x + v.y * v.y + v.z * v.z + v.w * v.w;
  }
  for (int off = 32; off >= 1; off >>= 1) {
    sum += __shfl_down(sum, off, 64);
    sq  += __shfl_down(sq,  off, 64);
  }
  __shared__ float ps[4], pq[4];
  if ((t & 63) == 0) { ps[t >> 6] = sum; pq[t >> 6] = sq; }
  __syncthreads();
  if (t == 0) {
    int idx = ((b * 8 + g) * 8 + z) * 2;
    part[idx + 0] = ps[0] + ps[1] + ps[2] + ps[3];
    part[idx + 1] = pq[0] + pq[1] + pq[2] + pq[3];
  }
}

// ---------------------------------------------------------------------------
// GN finish + apply + transpose: hT[b][n][c] bf16.
// ---------------------------------------------------------------------------
__global__ __launch_bounds__(256) void gn_apply_kernel(
    const float* __restrict__ x, const float* __restrict__ part,
    const float* __restrict__ gn_w, const float* __restrict__ gn_b,
    unsigned short* __restrict__ hT) {
  const int n0 = blockIdx.x * 64;
  const int c0 = blockIdx.y * 64;
  const int b  = blockIdx.z;
  const int t  = threadIdx.x;
  __shared__ unsigned short Ht[64 * 64];
  __shared__ float ls[64], lsh[64];
  if (t < 64) {
    int c = c0 + t;
    int g = c >> 5;
    float S = 0.f, Q = 0.f;
#pragma unroll
    for (int z = 0; z < 8; ++z) {
      int idx = ((b * 8 + g) * 8 + z) * 2;
      S += part[idx + 0];
      Q += part[idx + 1];
    }
    const float inv_cnt = 1.f / (32.f * N_PIX);
    float mu  = S * inv_cnt;
    float var = Q * inv_cnt - mu * mu;
    float rstd = rsqrtf(var + 1e-5f);
    float s = rstd * gn_w[c];
    ls[t]  = s;
    lsh[t] = gn_b[c] - mu * s;
  }
  __syncthreads();
  const int cl = t >> 4;
  const int nl = (t & 15) * 4;
#pragma unroll
  for (int r = 0; r < 4; ++r) {
    int ce = cl + r * 16;
    float sv = ls[ce], sh = lsh[ce];
    float4 v =
        *(const float4*)(x + ((size_t)(b * C_CH + c0 + ce)) * N_PIX + n0 + nl);
#pragma unroll
    for (int i = 0; i < 4; ++i) {
      float f = ((const float*)&v)[i] * sv + sh;
      Ht[swz(nl + i, ce >> 3) + (ce & 7)] = f2bf(f);
    }
  }
  __syncthreads();
  {
    const int row = t >> 2, sg = (t & 3) * 2;
    uint4 o0 = *(const uint4*)&Ht[swz(row, sg + 0)];
    uint4 o1 = *(const uint4*)&Ht[swz(row, sg + 1)];
    size_t go = ((size_t)(b * N_PIX + n0 + row)) * C_CH + c0 + sg * 8;
    *(uint4*)(hT + go) = o0;
    *(uint4*)(hT + go + 8) = o1;
  }
}

// ---------------------------------------------------------------------------
// QKV GEMM, bf16 MFMA, double-buffered K-loop (1 barrier/iter, reg prefetch).
// grid (12, 32, 4): type=x>>2 (0=Q,1=K,2=V), head=x&3.
// ---------------------------------------------------------------------------
__global__ __launch_bounds__(256) void qkv_gemm_kernel(
    const unsigned short* __restrict__ hT, const unsigned short* __restrict__ wB,
    const float* __restrict__ bqkv, unsigned short* __restrict__ qT,
    unsigned short* __restrict__ kT, unsigned short* __restrict__ vO) {
  const int mb = blockIdx.x, type = mb >> 2, head = mb & 3;
  const int n0 = blockIdx.y * 128;
  const int b  = blockIdx.z;
  const int t  = threadIdx.x;
  const int wave = t >> 6, lane = t & 63, quad = lane >> 4, lc = lane & 15;

  __shared__ unsigned short Ws[2 * 64 * 64];
  __shared__ unsigned short Hs[2 * 128 * 64];

  f32x4 acc[4][2];
#pragma unroll
  for (int i = 0; i < 4; ++i)
#pragma unroll
    for (int j = 0; j < 2; ++j) acc[i][j] = (f32x4){0.f, 0.f, 0.f, 0.f};

  const int wrow = t >> 2, wgb = (t & 3) * 2;
  const int hrow = t >> 1, hgb = (t & 1) * 4;
  const unsigned short* wp = wB + (size_t)(mb * 64 + wrow) * C_CH + wgb * 8;
  const unsigned short* ap =
      hT + ((size_t)(b * N_PIX + n0 + hrow)) * C_CH + hgb * 8;
  const int wsw0 = swz(wrow, wgb + 0), wsw1 = swz(wrow, wgb + 1);
  int hsw[4];
#pragma unroll
  for (int j = 0; j < 4; ++j) hsw[j] = swz(hrow, hgb + j);

  // prologue: stage k0=0 into buffer 0
  {
    uint4 w0 = *(const uint4*)(wp);
    uint4 w1 = *(const uint4*)(wp + 8);
    *(uint4*)&Ws[wsw0] = w0;
    *(uint4*)&Ws[wsw1] = w1;
#pragma unroll
    for (int j = 0; j < 4; ++j) {
      uint4 u = *(const uint4*)(ap + j * 8);
      *(uint4*)&Hs[hsw[j]] = u;
    }
  }
  __syncthreads();

  for (int kc = 0; kc < 4; ++kc) {
    const int cw = (kc & 1) * 4096, ch = (kc & 1) * 8192;
    const int nw = 4096 - cw, nh = 8192 - ch;
    const int kn = ((kc + 1) & 3) * 64;
    // prefetch next K-chunk
    uint4 pw0 = *(const uint4*)(wp + kn);
    uint4 pw1 = *(const uint4*)(wp + kn + 8);
    uint4 ph[4];
#pragma unroll
    for (int j = 0; j < 4; ++j) ph[j] = *(const uint4*)(ap + kn + j * 8);
    // compute on current buffer
#pragma unroll
    for (int kh = 0; kh < 2; ++kh) {
      bf16x8 wf[4], hf[2];
#pragma unroll
      for (int mt = 0; mt < 4; ++mt)
        wf[mt] = *(const bf16x8*)&Ws[cw + swz(mt * 16 + lc, kh * 4 + quad)];
#pragma unroll
      for (int nt = 0; nt < 2; ++nt)
        hf[nt] =
            *(const bf16x8*)&Hs[ch + swz(wave * 32 + nt * 16 + lc, kh * 4 + quad)];
      if (type < 2) {
#pragma unroll
        for (int mt = 0; mt < 4; ++mt)
#pragma unroll
          for (int nt = 0; nt < 2; ++nt)
            acc[mt][nt] = __builtin_amdgcn_mfma_f32_16x16x32_bf16(
                wf[mt], hf[nt], acc[mt][nt], 0, 0, 0);
      } else {
#pragma unroll
        for (int mt = 0; mt < 4; ++mt)
#pragma unroll
          for (int nt = 0; nt < 2; ++nt)
            acc[mt][nt] = __builtin_amdgcn_mfma_f32_16x16x32_bf16(
                hf[nt], wf[mt], acc[mt][nt], 0, 0, 0);
      }
    }
    // write next buffer (wasted on last iter; keeps code uniform)
    *(uint4*)&Ws[nw + wsw0] = pw0;
    *(uint4*)&Ws[nw + wsw1] = pw1;
#pragma unroll
    for (int j = 0; j < 4; ++j) *(uint4*)&Hs[nh + hsw[j]] = ph[j];
    __syncthreads();
  }

  if (type < 2) {
    unsigned short* dst = (type == 0) ? qT : kT;
    const float qs = (type == 0) ? 0.125f * 1.44269504f : 1.0f;
#pragma unroll
    for (int mt = 0; mt < 4; ++mt)
#pragma unroll
      for (int nt = 0; nt < 2; ++nt) {
        int n = n0 + wave * 32 + nt * 16 + lc;
        int d0 = mt * 16 + quad * 4;
        float b0 = bqkv[mb * 64 + d0 + 0], b1 = bqkv[mb * 64 + d0 + 1];
        float b2 = bqkv[mb * 64 + d0 + 2], b3 = bqkv[mb * 64 + d0 + 3];
        uint2 w;
        w.x = pk2((acc[mt][nt][0] + b0) * qs, (acc[mt][nt][1] + b1) * qs);
        w.y = pk2((acc[mt][nt][2] + b2) * qs, (acc[mt][nt][3] + b3) * qs);
        *(uint2*)(dst + ((size_t)((b * NH + head) * N_PIX + n)) * 64 + d0) = w;
      }
  } else {
#pragma unroll
    for (int mt = 0; mt < 4; ++mt)
#pragma unroll
      for (int nt = 0; nt < 2; ++nt) {
        int d = mt * 16 + lc;
        float bias = bqkv[mb * 64 + d];
        int pix = n0 + wave * 32 + nt * 16 + quad * 4;
        uint2 w;
        w.x = pk2(acc[mt][nt][0] + bias, acc[mt][nt][1] + bias);
        w.y = pk2(acc[mt][nt][2] + bias, acc[mt][nt][3] + bias);
        *(uint2*)(vO + ((size_t)((b * NH + head) * 64 + d)) * N_PIX + pix) = w;
      }
  }
}

// ---------------------------------------------------------------------------
// Flash attention, bf16 MFMA, static softmax, Q=128 tile, DOUBLE-BUFFERED
// K/V (register prefetch issued before compute, ONE barrier per iter).
// LDS: Qt/Ps 16KB + Kt 2x8KB + Vs 2x8KB = 48 KB.
// ---------------------------------------------------------------------------
__global__ __launch_bounds__(256) void attn_kernel(
    const unsigned short* __restrict__ qT, const unsigned short* __restrict__ kT,
    const unsigned short* __restrict__ vO, unsigned short* __restrict__ aT) {
  const int t  = threadIdx.x;
  const int i0 = blockIdx.x * 128;
  const int h  = blockIdx.y;
  const int b  = blockIdx.z;
  const size_t bh = (size_t)(b * NH + h);
  const unsigned short* qp = qT + bh * N_PIX * 64;
  const unsigned short* kp = kT + bh * N_PIX * 64;
  const unsigned short* vp = vO + bh * 64 * N_PIX;

  __shared__ unsigned short Qt[128 * 64];  // reused as Ps after Q frag loads
  __shared__ unsigned short Kt[2 * 64 * 64];
  __shared__ unsigned short Vs[2 * 64 * 64];
  unsigned short* const Ps = Qt;

  const int wave = t >> 6, lane = t & 63, quad = lane >> 4, lc = lane & 15;
  const int qb0 = wave * 32, qb1 = wave * 32 + 16;
  const int srow = t >> 2, sg = (t & 3) * 2;
  const int qrow = t >> 1, qg = (t & 1) * 4;

  // ---- stage Q, load frags (Qt dead afterward)
  {
    const unsigned short* s = qp + (size_t)(i0 + qrow) * 64 + qg * 8;
#pragma unroll
    for (int i = 0; i < 4; ++i) {
      uint4 u = *(const uint4*)(s + i * 8);
      *(uint4*)&Qt[swz(qrow, qg + i)] = u;
    }
  }
  __syncthreads();
  bf16x8 aq[2][2];
  aq[0][0] = *(const bf16x8*)&Qt[swz(qb0 + lc, quad)];
  aq[0][1] = *(const bf16x8*)&Qt[swz(qb0 + lc, quad + 4)];
  aq[1][0] = *(const bf16x8*)&Qt[swz(qb1 + lc, quad)];
  aq[1][1] = *(const bf16x8*)&Qt[swz(qb1 + lc, quad + 4)];

  int kof0[4], kof1[4], vof0[4], vof1[4], pw[2][4];
#pragma unroll
  for (int jt = 0; jt < 4; ++jt) {
    kof0[jt] = swz(jt * 16 + lc, quad);
    kof1[jt] = swz(jt * 16 + lc, quad + 4);
    pw[0][jt] = swz(qb0 + lc, jt * 2 + (quad >> 1)) + (quad & 1) * 4;
    pw[1][jt] = swz(qb1 + lc, jt * 2 + (quad >> 1)) + (quad & 1) * 4;
  }
#pragma unroll
  for (int mt = 0; mt < 4; ++mt) {
    vof0[mt] = swz(mt * 16 + lc, quad);
    vof1[mt] = swz(mt * 16 + lc, quad + 4);
  }
  const int pb00 = swz(qb0 + lc, quad), pb01 = swz(qb0 + lc, quad + 4);
  const int pb10 = swz(qb1 + lc, quad), pb11 = swz(qb1 + lc, quad + 4);
  const bf16x8 ones = {16256, 16256, 16256, 16256, 16256, 16256, 16256, 16256};
  const int wsw0 = swz(srow, sg + 0), wsw1 = swz(srow, sg + 1);

  // ---- prologue: stage K/V tile 0 into buffer 0
  {
    const unsigned short* sk = kp + (size_t)srow * 64 + sg * 8;
    const unsigned short* sv = vp + (size_t)srow * N_PIX + sg * 8;
    uint4 k0 = *(const uint4*)(sk);
    uint4 k1 = *(const uint4*)(sk + 8);
    uint4 v0 = *(const uint4*)(sv);
    uint4 v1 = *(const uint4*)(sv + 8);
    *(uint4*)&Kt[wsw0] = k0;
    *(uint4*)&Kt[wsw1] = k1;
    *(uint4*)&Vs[wsw0] = v0;
    *(uint4*)&Vs[wsw1] = v1;
  }
  __syncthreads();

  f32x4 la0 = (f32x4){0.f, 0.f, 0.f, 0.f};
  f32x4 la1 = (f32x4){0.f, 0.f, 0.f, 0.f};
  f32x4 od[2][4];
#pragma unroll
  for (int qh = 0; qh < 2; ++qh)
#pragma unroll
    for (int mt = 0; mt < 4; ++mt) od[qh][mt] = (f32x4){0.f, 0.f, 0.f, 0.f};

  for (int it = 0; it < 64; ++it) {
    const int cb = (it & 1) << 12;   // compute-buffer base (elems)
    const int nb = 4096 - cb;        // next-buffer base
    const int jn = ((it + 1) & 63) * 64;  // next tile start (wraps)

    // ---- prefetch next K/V tile into registers (latency overlapped)
    const unsigned short* snk = kp + (size_t)(jn + srow) * 64 + sg * 8;
    const unsigned short* snv = vp + (size_t)srow * N_PIX + jn + sg * 8;
    uint4 pk0 = *(const uint4*)(snk);
    uint4 pk1 = *(const uint4*)(snk + 8);
    uint4 pv0 = *(const uint4*)(snv);
    uint4 pv1 = *(const uint4*)(snv + 8);

    // ---- S^T = K*Q^T; p = exp2(s); P write (wave-private rows)
#pragma unroll
    for (int jt = 0; jt < 4; ++jt) {
      bf16x8 bk0 = *(const bf16x8*)&Kt[cb + kof0[jt]];
      bf16x8 bk1 = *(const bf16x8*)&Kt[cb + kof1[jt]];
      f32x4 a0 = (f32x4){0.f, 0.f, 0.f, 0.f};
      a0 = __builtin_amdgcn_mfma_f32_16x16x32_bf16(bk0, aq[0][0], a0, 0, 0, 0);
      a0 = __builtin_amdgcn_mfma_f32_16x16x32_bf16(bk1, aq[0][1], a0, 0, 0, 0);
      f32x4 a1 = (f32x4){0.f, 0.f, 0.f, 0.f};
      a1 = __builtin_amdgcn_mfma_f32_16x16x32_bf16(bk0, aq[1][0], a1, 0, 0, 0);
      a1 = __builtin_amdgcn_mfma_f32_16x16x32_bf16(bk1, aq[1][1], a1, 0, 0, 0);
      uint2 u0, u1;
      u0.x = pk2t(EXP2(a0[0]), EXP2(a0[1]));
      u0.y = pk2t(EXP2(a0[2]), EXP2(a0[3]));
      u1.x = pk2t(EXP2(a1[0]), EXP2(a1[1]));
      u1.y = pk2t(EXP2(a1[2]), EXP2(a1[3]));
      *(uint2*)&Ps[pw[0][jt]] = u0;
      *(uint2*)&Ps[pw[1][jt]] = u1;
    }

    // ---- P frags, l, PV
    bf16x8 bp00 = *(const bf16x8*)&Ps[pb00];
    bf16x8 bp01 = *(const bf16x8*)&Ps[pb01];
    bf16x8 bp10 = *(const bf16x8*)&Ps[pb10];
    bf16x8 bp11 = *(const bf16x8*)&Ps[pb11];
    la0 = __builtin_amdgcn_mfma_f32_16x16x32_bf16(ones, bp00, la0, 0, 0, 0);
    la0 = __builtin_amdgcn_mfma_f32_16x16x32_bf16(ones, bp01, la0, 0, 0, 0);
    la1 = __builtin_amdgcn_mfma_f32_16x16x32_bf16(ones, bp10, la1, 0, 0, 0);
    la1 = __builtin_amdgcn_mfma_f32_16x16x32_bf16(ones, bp11, la1, 0, 0, 0);
#pragma unroll
    for (int mt = 0; mt < 4; ++mt) {
      bf16x8 av0 = *(const bf16x8*)&Vs[cb + vof0[mt]];
      bf16x8 av1 = *(const bf16x8*)&Vs[cb + vof1[mt]];
      od[0][mt] =
          __builtin_amdgcn_mfma_f32_16x16x32_bf16(av0, bp00, od[0][mt], 0, 0, 0);
      od[0][mt] =
          __builtin_amdgcn_mfma_f32_16x16x32_bf16(av1, bp01, od[0][mt], 0, 0, 0);
      od[1][mt] =
          __builtin_amdgcn_mfma_f32_16x16x32_bf16(av0, bp10, od[1][mt], 0, 0, 0);
      od[1][mt] =
          __builtin_amdgcn_mfma_f32_16x16x32_bf16(av1, bp11, od[1][mt], 0, 0, 0);
    }

    // ---- write next buffer; one barrier per iter
    *(uint4*)&Kt[nb + wsw0] = pk0;
    *(uint4*)&Kt[nb + wsw1] = pk1;
    *(uint4*)&Vs[nb + wsw0] = pv0;
    *(uint4*)&Vs[nb + wsw1] = pv1;
    __syncthreads();
  }

  // ---- epilogue: O^T -> Ps[q][d] (own rows), coalesced [n][c] stores
  float inv0 = 1.f / la0[0];
  float inv1 = 1.f / la1[0];
#pragma unroll
  for (int mt = 0; mt < 4; ++mt) {
    uint2 u0, u1;
    u0.x = pk2(od[0][mt][0] * inv0, od[0][mt][1] * inv0);
    u0.y = pk2(od[0][mt][2] * inv0, od[0][mt][3] * inv0);
    u1.x = pk2(od[1][mt][0] * inv1, od[1][mt][1] * inv1);
    u1.y = pk2(od[1][mt][2] * inv1, od[1][mt][3] * inv1);
    *(uint2*)&Ps[swz(qb0 + lc, mt * 2 + (quad >> 1)) + (quad & 1) * 4] = u0;
    *(uint2*)&Ps[swz(qb1 + lc, mt * 2 + (quad >> 1)) + (quad & 1) * 4] = u1;
  }
  __syncthreads();
  {
    size_t go = ((size_t)(b * N_PIX + i0 + qrow)) * C_CH + h * 64 + qg * 8;
#pragma unroll
    for (int i = 0; i < 4; ++i) {
      uint4 o = *(const uint4*)&Ps[swz(qrow, qg + i)];
      *(uint4*)(aT + go + i * 8) = o;
    }
  }
}

// ---------------------------------------------------------------------------
// Proj GEMM, bf16 MFMA, double-buffered K-loop + fp32 bias/residual.
// ---------------------------------------------------------------------------
__global__ __launch_bounds__(256) void proj_gemm_kernel(
    const unsigned short* __restrict__ aT, const unsigned short* __restrict__ wPB,
    const float* __restrict__ bproj, const float* __restrict__ x,
    float* __restrict__ out) {
  const int m0 = blockIdx.x * 64;
  const int n0 = blockIdx.y * 128;
  const int b  = blockIdx.z;
  const int t  = threadIdx.x;
  const int wave = t >> 6, lane = t & 63, quad = lane >> 4, lc = lane & 15;

  __shared__ unsigned short Ws[2 * 64 * 64];
  __shared__ unsigned short Hs[2 * 128 * 64];

  f32x4 acc[4][2];
#pragma unroll
  for (int i = 0; i < 4; ++i)
#pragma unroll
    for (int j = 0; j < 2; ++j) acc[i][j] = (f32x4){0.f, 0.f, 0.f, 0.f};

  const int wrow = t >> 2, wgb = (t & 3) * 2;
  const int hrow = t >> 1, hgb = (t & 1) * 4;
  const unsigned short* wp = wPB + (size_t)(m0 + wrow) * C_CH + wgb * 8;
  const unsigned short* ap =
      aT + ((size_t)(b * N_PIX + n0 + hrow)) * C_CH + hgb * 8;
  const int wsw0 = swz(wrow, wgb + 0), wsw1 = swz(wrow, wgb + 1);
  int hsw[4];
#pragma unroll
  for (int j = 0; j < 4; ++j) hsw[j] = swz(hrow, hgb + j);

  {
    uint4 w0 = *(const uint4*)(wp);
    uint4 w1 = *(const uint4*)(wp + 8);
    *(uint4*)&Ws[wsw0] = w0;
    *(uint4*)&Ws[wsw1] = w1;
#pragma unroll
    for (int j = 0; j < 4; ++j) {
      uint4 u = *(const uint4*)(ap + j * 8);
      *(uint4*)&Hs[hsw[j]] = u;
    }
  }
  __syncthreads();

  for (int kc = 0; kc < 4; ++kc) {
    const int cw = (kc & 1) * 4096, ch = (kc & 1) * 8192;
    const int nw = 4096 - cw, nh = 8192 - ch;
    const int kn = ((kc + 1) & 3) * 64;
    uint4 pw0 = *(const uint4*)(wp + kn);
    uint4 pw1 = *(const uint4*)(wp + kn + 8);
    uint4 ph[4];
#pragma unroll
    for (int j = 0; j < 4; ++j) ph[j] = *(const uint4*)(ap + kn + j * 8);
#pragma unroll
    for (int kh = 0; kh < 2; ++kh) {
      bf16x8 wf[4], hf[2];
#pragma unroll
      for (int mt = 0; mt < 4; ++mt)
        wf[mt] = *(const bf16x8*)&Ws[cw + swz(mt * 16 + lc, kh * 4 + quad)];
#pragma unroll
      for (int nt = 0; nt < 2; ++nt)
        hf[nt] =
            *(const bf16x8*)&Hs[ch + swz(wave * 32 + nt * 16 + lc, kh * 4 + quad)];
#pragma unroll
      for (int mt = 0; mt < 4; ++mt)
#pragma unroll
        for (int nt = 0; nt < 2; ++nt)
          acc[mt][nt] = __builtin_amdgcn_mfma_f32_16x16x32_bf16(
              wf[mt], hf[nt], acc[mt][nt], 0, 0, 0);
    }
    *(uint4*)&Ws[nw + wsw0] = pw0;
    *(uint4*)&Ws[nw + wsw1] = pw1;
#pragma unroll
    for (int j = 0; j < 4; ++j) *(uint4*)&Hs[nh + hsw[j]] = ph[j];
    __syncthreads();
  }
#pragma unroll
  for (int mt = 0; mt < 4; ++mt) {
#pragma unroll
    for (int nt = 0; nt < 2; ++nt) {
      int n = n0 + wave * 32 + nt * 16 + lc;
#pragma unroll
      for (int r = 0; r < 4; ++r) {
        int c = m0 + mt * 16 + quad * 4 + r;
        size_t gi = ((size_t)(b * C_CH + c)) * N_PIX + n;
        out[gi] = acc[mt][nt][r] + bproj[c] + x[gi];
      }
    }
  }
}

// ---------------------------------------------------------------------------
extern "C" void kernel_launch(void* const* d_in, const int* in_sizes, int n_in,
                              void* d_out, int out_size, void* d_ws,
                              size_t ws_size, hipStream_t stream) {
  const float* x      = (const float*)d_in[0];
  const float* gn_w   = (const float*)d_in[1];
  const float* gn_b   = (const float*)d_in[2];
  const float* w_qkv  = (const float*)d_in[3];
  const float* b_qkv  = (const float*)d_in[4];
  const float* w_proj = (const float*)d_in[5];
  const float* b_proj = (const float*)d_in[6];
  float* out = (float*)d_out;

  float* ws   = (float*)d_ws;
  float* part = ws + 2048;
  unsigned short* qT = (unsigned short*)(ws + 4096);
  unsigned short* kT = qT + (size_t)4194304;
  unsigned short* vO = kT + (size_t)4194304;
  unsigned short* aT = vO + (size_t)4194304;
  unsigned short* hT = aT + (size_t)4194304;
  unsigned short* wB = hT + (size_t)4 * N_PIX * C_CH;
  unsigned short* wPB = wB + (size_t)49152 * 4;

  gn_part_kernel<<<dim3(8, 4, 8), dim3(256), 0, stream>>>(x, w_qkv, w_proj,
                                                          part, wB);
  gn_apply_kernel<<<dim3(64, 4, 4), dim3(256), 0, stream>>>(x, part, gn_w,
                                                            gn_b, hT);
  qkv_gemm_kernel<<<dim3(12, 32, 4), dim3(256), 0, stream>>>(
      hT, wB, b_qkv, qT, kT, vO);
  attn_kernel<<<dim3(32, 4, 4), dim3(256), 0, stream>>>(qT, kT, vO, aT);
  proj_gemm_kernel<<<dim3(4, 32, 4), dim3(256), 0, stream>>>(
      aT, wPB, b_proj, x, out);
}

// Round 8
// 232.918 us; speedup vs baseline: 1.0012x; 1.0012x over previous
//
#include <hip/hip_runtime.h>
#include <math.h>

#define N_PIX 4096   // H*W
#define C_CH  256
#define NH    4
#define DH    64

typedef __attribute__((ext_vector_type(8))) short bf16x8;
typedef __attribute__((ext_vector_type(4))) float f32x4;

static __device__ __forceinline__ unsigned short f2bf(float f) {
  union { float f; unsigned u; } v; v.f = f;
  unsigned r = v.u + 0x7fffu + ((v.u >> 16) & 1u);  // RNE
  return (unsigned short)(r >> 16);
}
static __device__ __forceinline__ unsigned pk2(float a, float b) {
  return (unsigned)f2bf(a) | ((unsigned)f2bf(b) << 16);
}
// trunc-pack two fp32 -> bf16 pair in ONE v_perm_b32
static __device__ __forceinline__ unsigned pk2t(float a, float b) {
  return __builtin_amdgcn_perm(__float_as_uint(b), __float_as_uint(a),
                               0x07060302u);
}
static __device__ __forceinline__ float bflo(unsigned u) {
  return __uint_as_float(u << 16);
}
static __device__ __forceinline__ float bfhi(unsigned u) {
  return __uint_as_float(u & 0xffff0000u);
}
#if __has_builtin(__builtin_amdgcn_exp2f)
#define EXP2(x) __builtin_amdgcn_exp2f(x)
#else
#define EXP2(x) exp2f(x)
#endif
// XOR-swizzled LDS offset (bf16 elems): rows of 64 elems, 8 granules of 8.
static __device__ __forceinline__ int swz(int row, int g) {
  return (row << 6) + ((((row >> 2) ^ row ^ g) & 7) << 3);
}

// ---------------------------------------------------------------------------
// GroupNorm stage A (partial sums) + weight fp32->bf16 convert (fused).
// ---------------------------------------------------------------------------
__global__ __launch_bounds__(256) void gn_part_kernel(
    const float* __restrict__ x, const float* __restrict__ wqkv,
    const float* __restrict__ wproj, float* __restrict__ part,
    unsigned short* __restrict__ wB) {
  const int g = blockIdx.x, b = blockIdx.y, z = blockIdx.z;
  const int t = threadIdx.x;
  {
    const int bid = blockIdx.z * 32 + blockIdx.y * 8 + blockIdx.x;
    const int i = bid * 256 + t;
    const float* src = (i < 49152) ? (wqkv + (size_t)i * 4)
                                   : (wproj + (size_t)(i - 49152) * 4);
    float4 v = *(const float4*)src;
    uint2 u;
    u.x = pk2(v.x, v.y);
    u.y = pk2(v.z, v.w);
    *(uint2*)(wB + (size_t)i * 4) = u;
  }
  const float* base = x + (size_t)(b * C_CH + g * 32 + z * 4) * N_PIX;
  float sum = 0.f, sq = 0.f;
  for (int i = t * 4; i < 4 * N_PIX; i += 256 * 4) {
    float4 v = *(const float4*)(base + i);
    sum += v.x + v.y + v.z + v.w;
    sq  += v.x * v.x + v.y * v.y + v.z * v.z + v.w * v.w;
  }
  for (int off = 32; off >= 1; off >>= 1) {
    sum += __shfl_down(sum, off, 64);
    sq  += __shfl_down(sq,  off, 64);
  }
  __shared__ float ps[4], pq[4];
  if ((t & 63) == 0) { ps[t >> 6] = sum; pq[t >> 6] = sq; }
  __syncthreads();
  if (t == 0) {
    int idx = ((b * 8 + g) * 8 + z) * 2;
    part[idx + 0] = ps[0] + ps[1] + ps[2] + ps[3];
    part[idx + 1] = pq[0] + pq[1] + pq[2] + pq[3];
  }
}

// ---------------------------------------------------------------------------
// GN finish + apply + transpose: hT[b][n][c] bf16.
// ---------------------------------------------------------------------------
__global__ __launch_bounds__(256) void gn_apply_kernel(
    const float* __restrict__ x, const float* __restrict__ part,
    const float* __restrict__ gn_w, const float* __restrict__ gn_b,
    unsigned short* __restrict__ hT) {
  const int n0 = blockIdx.x * 64;
  const int c0 = blockIdx.y * 64;
  const int b  = blockIdx.z;
  const int t  = threadIdx.x;
  __shared__ unsigned short Ht[64 * 64];
  __shared__ float ls[64], lsh[64];
  if (t < 64) {
    int c = c0 + t;
    int g = c >> 5;
    float S = 0.f, Q = 0.f;
#pragma unroll
    for (int z = 0; z < 8; ++z) {
      int idx = ((b * 8 + g) * 8 + z) * 2;
      S += part[idx + 0];
      Q += part[idx + 1];
    }
    const float inv_cnt = 1.f / (32.f * N_PIX);
    float mu  = S * inv_cnt;
    float var = Q * inv_cnt - mu * mu;
    float rstd = rsqrtf(var + 1e-5f);
    float s = rstd * gn_w[c];
    ls[t]  = s;
    lsh[t] = gn_b[c] - mu * s;
  }
  __syncthreads();
  const int cl = t >> 4;
  const int nl = (t & 15) * 4;
#pragma unroll
  for (int r = 0; r < 4; ++r) {
    int ce = cl + r * 16;
    float sv = ls[ce], sh = lsh[ce];
    float4 v =
        *(const float4*)(x + ((size_t)(b * C_CH + c0 + ce)) * N_PIX + n0 + nl);
#pragma unroll
    for (int i = 0; i < 4; ++i) {
      float f = ((const float*)&v)[i] * sv + sh;
      Ht[swz(nl + i, ce >> 3) + (ce & 7)] = f2bf(f);
    }
  }
  __syncthreads();
  {
    const int row = t >> 2, sg = (t & 3) * 2;
    uint4 o0 = *(const uint4*)&Ht[swz(row, sg + 0)];
    uint4 o1 = *(const uint4*)&Ht[swz(row, sg + 1)];
    size_t go = ((size_t)(b * N_PIX + n0 + row)) * C_CH + c0 + sg * 8;
    *(uint4*)(hT + go) = o0;
    *(uint4*)(hT + go + 8) = o1;
  }
}

// ---------------------------------------------------------------------------
// QKV GEMM, bf16 MFMA, single-buffer (r6 version).
// grid (12, 32, 4): type=x>>2 (0=Q,1=K,2=V), head=x&3.
// ---------------------------------------------------------------------------
__global__ __launch_bounds__(256) void qkv_gemm_kernel(
    const unsigned short* __restrict__ hT, const unsigned short* __restrict__ wB,
    const float* __restrict__ bqkv, unsigned short* __restrict__ qT,
    unsigned short* __restrict__ kT, unsigned short* __restrict__ vO) {
  const int mb = blockIdx.x, type = mb >> 2, head = mb & 3;
  const int n0 = blockIdx.y * 128;
  const int b  = blockIdx.z;
  const int t  = threadIdx.x;
  const int wave = t >> 6, lane = t & 63, quad = lane >> 4, lc = lane & 15;

  __shared__ unsigned short Ws[64 * 64];
  __shared__ unsigned short Hs[128 * 64];

  f32x4 acc[4][2];
#pragma unroll
  for (int i = 0; i < 4; ++i)
#pragma unroll
    for (int j = 0; j < 2; ++j) acc[i][j] = (f32x4){0.f, 0.f, 0.f, 0.f};

  const int wrow = t >> 2, wgb = (t & 3) * 2;
  const int hrow = t >> 1, hgb = (t & 1) * 4;
  const unsigned short* wp = wB + (size_t)(mb * 64 + wrow) * C_CH;
  const unsigned short* ap =
      hT + ((size_t)(b * N_PIX + n0 + hrow)) * C_CH + hgb * 8;

  for (int k0 = 0; k0 < C_CH; k0 += 64) {
    __syncthreads();
    {
      const unsigned short* s0 = wp + k0 + wgb * 8;
      uint4 u0 = *(const uint4*)(s0);
      uint4 u1 = *(const uint4*)(s0 + 8);
      *(uint4*)&Ws[swz(wrow, wgb + 0)] = u0;
      *(uint4*)&Ws[swz(wrow, wgb + 1)] = u1;
    }
    {
      const unsigned short* s0 = ap + k0;
#pragma unroll
      for (int j = 0; j < 4; ++j) {
        uint4 u = *(const uint4*)(s0 + j * 8);
        *(uint4*)&Hs[swz(hrow, hgb + j)] = u;
      }
    }
    __syncthreads();
#pragma unroll
    for (int kh = 0; kh < 2; ++kh) {
      bf16x8 wf[4], hf[2];
#pragma unroll
      for (int mt = 0; mt < 4; ++mt)
        wf[mt] = *(const bf16x8*)&Ws[swz(mt * 16 + lc, kh * 4 + quad)];
#pragma unroll
      for (int nt = 0; nt < 2; ++nt)
        hf[nt] = *(const bf16x8*)&Hs[swz(wave * 32 + nt * 16 + lc, kh * 4 + quad)];
      if (type < 2) {
#pragma unroll
        for (int mt = 0; mt < 4; ++mt)
#pragma unroll
          for (int nt = 0; nt < 2; ++nt)
            acc[mt][nt] = __builtin_amdgcn_mfma_f32_16x16x32_bf16(
                wf[mt], hf[nt], acc[mt][nt], 0, 0, 0);
      } else {
#pragma unroll
        for (int mt = 0; mt < 4; ++mt)
#pragma unroll
          for (int nt = 0; nt < 2; ++nt)
            acc[mt][nt] = __builtin_amdgcn_mfma_f32_16x16x32_bf16(
                hf[nt], wf[mt], acc[mt][nt], 0, 0, 0);
      }
    }
  }

  if (type < 2) {
    unsigned short* dst = (type == 0) ? qT : kT;
    const float qs = (type == 0) ? 0.125f * 1.44269504f : 1.0f;
#pragma unroll
    for (int mt = 0; mt < 4; ++mt)
#pragma unroll
      for (int nt = 0; nt < 2; ++nt) {
        int n = n0 + wave * 32 + nt * 16 + lc;
        int d0 = mt * 16 + quad * 4;
        float b0 = bqkv[mb * 64 + d0 + 0], b1 = bqkv[mb * 64 + d0 + 1];
        float b2 = bqkv[mb * 64 + d0 + 2], b3 = bqkv[mb * 64 + d0 + 3];
        uint2 w;
        w.x = pk2((acc[mt][nt][0] + b0) * qs, (acc[mt][nt][1] + b1) * qs);
        w.y = pk2((acc[mt][nt][2] + b2) * qs, (acc[mt][nt][3] + b3) * qs);
        *(uint2*)(dst + ((size_t)((b * NH + head) * N_PIX + n)) * 64 + d0) = w;
      }
  } else {
#pragma unroll
    for (int mt = 0; mt < 4; ++mt)
#pragma unroll
      for (int nt = 0; nt < 2; ++nt) {
        int d = mt * 16 + lc;
        float bias = bqkv[mb * 64 + d];
        int pix = n0 + wave * 32 + nt * 16 + quad * 4;
        uint2 w;
        w.x = pk2(acc[mt][nt][0] + bias, acc[mt][nt][1] + bias);
        w.y = pk2(acc[mt][nt][2] + bias, acc[mt][nt][3] + bias);
        *(uint2*)(vO + ((size_t)((b * NH + head) * 64 + d)) * N_PIX + pix) = w;
      }
  }
}

// ---------------------------------------------------------------------------
// Flash attention, SPLIT-K (2 splits x 2048 keys), static softmax, Q=128.
// grid (32 qtiles, NH, 8): z = b*2+s. 1024 blocks -> 4 blocks/CU.
// Writes UNNORMALIZED partial O (bf16, [n][c] layout) + partial l (fp32);
// combine_kernel sums splits and normalizes. LDS 32 KB single-buffer.
// ---------------------------------------------------------------------------
__global__ __launch_bounds__(256) void attn_kernel(
    const unsigned short* __restrict__ qT, const unsigned short* __restrict__ kT,
    const unsigned short* __restrict__ vO, unsigned short* __restrict__ oP,
    float* __restrict__ lP) {
  const int t  = threadIdx.x;
  const int i0 = blockIdx.x * 128;
  const int h  = blockIdx.y;
  const int b  = blockIdx.z >> 1;
  const int s  = blockIdx.z & 1;
  const int bh = b * NH + h;
  const size_t bhs = (size_t)bh;
  const unsigned short* qp = qT + bhs * N_PIX * 64;
  const unsigned short* kp = kT + bhs * N_PIX * 64;
  const unsigned short* vp = vO + bhs * 64 * N_PIX;

  __shared__ unsigned short Qt[128 * 64];  // reused as Ps after Q frag loads
  __shared__ unsigned short Kt[64 * 64];
  __shared__ unsigned short Vs[64 * 64];
  unsigned short* const Ps = Qt;

  const int wave = t >> 6, lane = t & 63, quad = lane >> 4, lc = lane & 15;
  const int qb0 = wave * 32, qb1 = wave * 32 + 16;
  const int srow = t >> 2, sg = (t & 3) * 2;
  const int qrow = t >> 1, qg = (t & 1) * 4;

  // ---- stage Q, load frags (Qt dead afterward)
  {
    const unsigned short* sp = qp + (size_t)(i0 + qrow) * 64 + qg * 8;
#pragma unroll
    for (int i = 0; i < 4; ++i) {
      uint4 u = *(const uint4*)(sp + i * 8);
      *(uint4*)&Qt[swz(qrow, qg + i)] = u;
    }
  }
  __syncthreads();
  bf16x8 aq[2][2];
  aq[0][0] = *(const bf16x8*)&Qt[swz(qb0 + lc, quad)];
  aq[0][1] = *(const bf16x8*)&Qt[swz(qb0 + lc, quad + 4)];
  aq[1][0] = *(const bf16x8*)&Qt[swz(qb1 + lc, quad)];
  aq[1][1] = *(const bf16x8*)&Qt[swz(qb1 + lc, quad + 4)];

  int kof0[4], kof1[4], vof0[4], vof1[4], pw[2][4];
#pragma unroll
  for (int jt = 0; jt < 4; ++jt) {
    kof0[jt] = swz(jt * 16 + lc, quad);
    kof1[jt] = swz(jt * 16 + lc, quad + 4);
    pw[0][jt] = swz(qb0 + lc, jt * 2 + (quad >> 1)) + (quad & 1) * 4;
    pw[1][jt] = swz(qb1 + lc, jt * 2 + (quad >> 1)) + (quad & 1) * 4;
  }
#pragma unroll
  for (int mt = 0; mt < 4; ++mt) {
    vof0[mt] = swz(mt * 16 + lc, quad);
    vof1[mt] = swz(mt * 16 + lc, quad + 4);
  }
  const int pb00 = swz(qb0 + lc, quad), pb01 = swz(qb0 + lc, quad + 4);
  const int pb10 = swz(qb1 + lc, quad), pb11 = swz(qb1 + lc, quad + 4);
  const bf16x8 ones = {16256, 16256, 16256, 16256, 16256, 16256, 16256, 16256};

  f32x4 la0 = (f32x4){0.f, 0.f, 0.f, 0.f};
  f32x4 la1 = (f32x4){0.f, 0.f, 0.f, 0.f};
  f32x4 od[2][4];
#pragma unroll
  for (int qh = 0; qh < 2; ++qh)
#pragma unroll
    for (int mt = 0; mt < 4; ++mt) od[qh][mt] = (f32x4){0.f, 0.f, 0.f, 0.f};

  const int jbase = s * 2048;
  for (int it = 0; it < 32; ++it) {
    const int j0 = jbase + it * 64;
    __syncthreads();  // prev iter's Kt/Vs frag reads done
    {
      const unsigned short* sk = kp + (size_t)(j0 + srow) * 64 + sg * 8;
      uint4 k0 = *(const uint4*)(sk);
      uint4 k1 = *(const uint4*)(sk + 8);
      *(uint4*)&Kt[swz(srow, sg + 0)] = k0;
      *(uint4*)&Kt[swz(srow, sg + 1)] = k1;
      const unsigned short* sv = vp + (size_t)srow * N_PIX + j0 + sg * 8;
      uint4 v0 = *(const uint4*)(sv);
      uint4 v1 = *(const uint4*)(sv + 8);
      *(uint4*)&Vs[swz(srow, sg + 0)] = v0;
      *(uint4*)&Vs[swz(srow, sg + 1)] = v1;
    }
    __syncthreads();

    // ---- S^T = K*Q^T; p = exp2(s); P write (wave-private rows)
#pragma unroll
    for (int jt = 0; jt < 4; ++jt) {
      bf16x8 bk0 = *(const bf16x8*)&Kt[kof0[jt]];
      bf16x8 bk1 = *(const bf16x8*)&Kt[kof1[jt]];
      f32x4 a0 = (f32x4){0.f, 0.f, 0.f, 0.f};
      a0 = __builtin_amdgcn_mfma_f32_16x16x32_bf16(bk0, aq[0][0], a0, 0, 0, 0);
      a0 = __builtin_amdgcn_mfma_f32_16x16x32_bf16(bk1, aq[0][1], a0, 0, 0, 0);
      f32x4 a1 = (f32x4){0.f, 0.f, 0.f, 0.f};
      a1 = __builtin_amdgcn_mfma_f32_16x16x32_bf16(bk0, aq[1][0], a1, 0, 0, 0);
      a1 = __builtin_amdgcn_mfma_f32_16x16x32_bf16(bk1, aq[1][1], a1, 0, 0, 0);
      uint2 u0, u1;
      u0.x = pk2t(EXP2(a0[0]), EXP2(a0[1]));
      u0.y = pk2t(EXP2(a0[2]), EXP2(a0[3]));
      u1.x = pk2t(EXP2(a1[0]), EXP2(a1[1]));
      u1.y = pk2t(EXP2(a1[2]), EXP2(a1[3]));
      *(uint2*)&Ps[pw[0][jt]] = u0;
      *(uint2*)&Ps[pw[1][jt]] = u1;
    }

    // ---- P frags, l, PV
    bf16x8 bp00 = *(const bf16x8*)&Ps[pb00];
    bf16x8 bp01 = *(const bf16x8*)&Ps[pb01];
    bf16x8 bp10 = *(const bf16x8*)&Ps[pb10];
    bf16x8 bp11 = *(const bf16x8*)&Ps[pb11];
    la0 = __builtin_amdgcn_mfma_f32_16x16x32_bf16(ones, bp00, la0, 0, 0, 0);
    la0 = __builtin_amdgcn_mfma_f32_16x16x32_bf16(ones, bp01, la0, 0, 0, 0);
    la1 = __builtin_amdgcn_mfma_f32_16x16x32_bf16(ones, bp10, la1, 0, 0, 0);
    la1 = __builtin_amdgcn_mfma_f32_16x16x32_bf16(ones, bp11, la1, 0, 0, 0);
#pragma unroll
    for (int mt = 0; mt < 4; ++mt) {
      bf16x8 av0 = *(const bf16x8*)&Vs[vof0[mt]];
      bf16x8 av1 = *(const bf16x8*)&Vs[vof1[mt]];
      od[0][mt] =
          __builtin_amdgcn_mfma_f32_16x16x32_bf16(av0, bp00, od[0][mt], 0, 0, 0);
      od[0][mt] =
          __builtin_amdgcn_mfma_f32_16x16x32_bf16(av1, bp01, od[0][mt], 0, 0, 0);
      od[1][mt] =
          __builtin_amdgcn_mfma_f32_16x16x32_bf16(av0, bp10, od[1][mt], 0, 0, 0);
      od[1][mt] =
          __builtin_amdgcn_mfma_f32_16x16x32_bf16(av1, bp11, od[1][mt], 0, 0, 0);
    }
  }

  // ---- partial l store (all quads hold same value; quad 0 writes)
  if (quad == 0) {
    float* lrow = lP + ((size_t)(s * 16 + bh)) * N_PIX + i0;
    lrow[qb0 + lc] = la0[0];
    lrow[qb1 + lc] = la1[0];
  }

  // ---- epilogue: UNNORMALIZED O^T -> Ps[q][d] (own rows), coalesced stores
#pragma unroll
  for (int mt = 0; mt < 4; ++mt) {
    uint2 u0, u1;
    u0.x = pk2(od[0][mt][0], od[0][mt][1]);
    u0.y = pk2(od[0][mt][2], od[0][mt][3]);
    u1.x = pk2(od[1][mt][0], od[1][mt][1]);
    u1.y = pk2(od[1][mt][2], od[1][mt][3]);
    *(uint2*)&Ps[swz(qb0 + lc, mt * 2 + (quad >> 1)) + (quad & 1) * 4] = u0;
    *(uint2*)&Ps[swz(qb1 + lc, mt * 2 + (quad >> 1)) + (quad & 1) * 4] = u1;
  }
  __syncthreads();
  {
    unsigned short* dst = oP + (size_t)s * 4194304;
    size_t go = ((size_t)(b * N_PIX + i0 + qrow)) * C_CH + h * 64 + qg * 8;
#pragma unroll
    for (int i = 0; i < 4; ++i) {
      uint4 o = *(const uint4*)&Ps[swz(qrow, qg + i)];
      *(uint4*)(dst + go + i * 8) = o;
    }
  }
}

// ---------------------------------------------------------------------------
// Combine: aT[b][n][c] = (oP0 + oP1) / (l0 + l1).  Elementwise, uint4 I/O.
// grid 2048 x 256 threads, 8 bf16 elems/thread.
// ---------------------------------------------------------------------------
__global__ __launch_bounds__(256) void combine_kernel(
    const unsigned short* __restrict__ oP, const float* __restrict__ lP,
    unsigned short* __restrict__ aT) {
  const size_t idx = ((size_t)blockIdx.x * 256 + threadIdx.x) * 8;
  const int c = (int)(idx & 255);
  const int n = (int)((idx >> 8) & 4095);
  const int b = (int)(idx >> 20);
  const int bh = b * NH + (c >> 6);
  float l = lP[(size_t)bh * N_PIX + n] + lP[(size_t)(16 + bh) * N_PIX + n];
  float inv = 1.f / l;
  uint4 u1 = *(const uint4*)(oP + idx);
  uint4 u2 = *(const uint4*)(oP + 4194304 + idx);
  uint4 r;
  r.x = pk2((bflo(u1.x) + bflo(u2.x)) * inv, (bfhi(u1.x) + bfhi(u2.x)) * inv);
  r.y = pk2((bflo(u1.y) + bflo(u2.y)) * inv, (bfhi(u1.y) + bfhi(u2.y)) * inv);
  r.z = pk2((bflo(u1.z) + bflo(u2.z)) * inv, (bfhi(u1.z) + bfhi(u2.z)) * inv);
  r.w = pk2((bflo(u1.w) + bflo(u2.w)) * inv, (bfhi(u1.w) + bfhi(u2.w)) * inv);
  *(uint4*)(aT + idx) = r;
}

// ---------------------------------------------------------------------------
// Proj GEMM, bf16 MFMA, single-buffer (r6 version) + fp32 bias/residual.
// ---------------------------------------------------------------------------
__global__ __launch_bounds__(256) void proj_gemm_kernel(
    const unsigned short* __restrict__ aT, const unsigned short* __restrict__ wPB,
    const float* __restrict__ bproj, const float* __restrict__ x,
    float* __restrict__ out) {
  const int m0 = blockIdx.x * 64;
  const int n0 = blockIdx.y * 128;
  const int b  = blockIdx.z;
  const int t  = threadIdx.x;
  const int wave = t >> 6, lane = t & 63, quad = lane >> 4, lc = lane & 15;

  __shared__ unsigned short Ws[64 * 64];
  __shared__ unsigned short Hs[128 * 64];

  f32x4 acc[4][2];
#pragma unroll
  for (int i = 0; i < 4; ++i)
#pragma unroll
    for (int j = 0; j < 2; ++j) acc[i][j] = (f32x4){0.f, 0.f, 0.f, 0.f};

  const int wrow = t >> 2, wgb = (t & 3) * 2;
  const int hrow = t >> 1, hgb = (t & 1) * 4;
  const unsigned short* wp = wPB + (size_t)(m0 + wrow) * C_CH;
  const unsigned short* ap =
      aT + ((size_t)(b * N_PIX + n0 + hrow)) * C_CH + hgb * 8;

  for (int k0 = 0; k0 < C_CH; k0 += 64) {
    __syncthreads();
    {
      const unsigned short* s0 = wp + k0 + wgb * 8;
      uint4 u0 = *(const uint4*)(s0);
      uint4 u1 = *(const uint4*)(s0 + 8);
      *(uint4*)&Ws[swz(wrow, wgb + 0)] = u0;
      *(uint4*)&Ws[swz(wrow, wgb + 1)] = u1;
    }
    {
      const unsigned short* s0 = ap + k0;
#pragma unroll
      for (int j = 0; j < 4; ++j) {
        uint4 u = *(const uint4*)(s0 + j * 8);
        *(uint4*)&Hs[swz(hrow, hgb + j)] = u;
      }
    }
    __syncthreads();
#pragma unroll
    for (int kh = 0; kh < 2; ++kh) {
      bf16x8 wf[4], hf[2];
#pragma unroll
      for (int mt = 0; mt < 4; ++mt)
        wf[mt] = *(const bf16x8*)&Ws[swz(mt * 16 + lc, kh * 4 + quad)];
#pragma unroll
      for (int nt = 0; nt < 2; ++nt)
        hf[nt] = *(const bf16x8*)&Hs[swz(wave * 32 + nt * 16 + lc, kh * 4 + quad)];
#pragma unroll
      for (int mt = 0; mt < 4; ++mt)
#pragma unroll
        for (int nt = 0; nt < 2; ++nt)
          acc[mt][nt] = __builtin_amdgcn_mfma_f32_16x16x32_bf16(
              wf[mt], hf[nt], acc[mt][nt], 0, 0, 0);
    }
  }
#pragma unroll
  for (int mt = 0; mt < 4; ++mt) {
#pragma unroll
    for (int nt = 0; nt < 2; ++nt) {
      int n = n0 + wave * 32 + nt * 16 + lc;
#pragma unroll
      for (int r = 0; r < 4; ++r) {
        int c = m0 + mt * 16 + quad * 4 + r;
        size_t gi = ((size_t)(b * C_CH + c)) * N_PIX + n;
        out[gi] = acc[mt][nt][r] + bproj[c] + x[gi];
      }
    }
  }
}

// ---------------------------------------------------------------------------
extern "C" void kernel_launch(void* const* d_in, const int* in_sizes, int n_in,
                              void* d_out, int out_size, void* d_ws,
                              size_t ws_size, hipStream_t stream) {
  const float* x      = (const float*)d_in[0];
  const float* gn_w   = (const float*)d_in[1];
  const float* gn_b   = (const float*)d_in[2];
  const float* w_qkv  = (const float*)d_in[3];
  const float* b_qkv  = (const float*)d_in[4];
  const float* w_proj = (const float*)d_in[5];
  const float* b_proj = (const float*)d_in[6];
  float* out = (float*)d_out;

  // ws: part[512]f @+2048 | pad to 4096f | bf16: qT,kT,vO,aT,hT (4.19M ea) |
  //     wB (262k) | oP (2x4.19M) | lP fp32 (131k)  -> ~60 MB total
  float* ws   = (float*)d_ws;
  float* part = ws + 2048;
  unsigned short* qT = (unsigned short*)(ws + 4096);
  unsigned short* kT = qT + (size_t)4194304;
  unsigned short* vO = kT + (size_t)4194304;
  unsigned short* aT = vO + (size_t)4194304;
  unsigned short* hT = aT + (size_t)4194304;
  unsigned short* wB = hT + (size_t)4194304;
  unsigned short* wPB = wB + (size_t)49152 * 4;
  unsigned short* oP = wB + (size_t)262144;
  float* lP = (float*)(oP + (size_t)8388608);

  gn_part_kernel<<<dim3(8, 4, 8), dim3(256), 0, stream>>>(x, w_qkv, w_proj,
                                                          part, wB);
  gn_apply_kernel<<<dim3(64, 4, 4), dim3(256), 0, stream>>>(x, part, gn_w,
                                                            gn_b, hT);
  qkv_gemm_kernel<<<dim3(12, 32, 4), dim3(256), 0, stream>>>(
      hT, wB, b_qkv, qT, kT, vO);
  attn_kernel<<<dim3(32, 4, 8), dim3(256), 0, stream>>>(qT, kT, vO, oP, lP);
  combine_kernel<<<dim3(2048), dim3(256), 0, stream>>>(oP, lP, aT);
  proj_gemm_kernel<<<dim3(4, 32, 4), dim3(256), 0, stream>>>(
      aT, wPB, b_proj, x, out);
}